// Round 2
// baseline (491.919 us; speedup 1.0000x reference)
//
#include <hip/hip_runtime.h>
#include <hip/hip_bf16.h>
#include <cstdint>
#include <cstddef>

#define D_IN  512
#define D_H   128
#define D_OUT 64
#define SB    256   // stats partial blocks (1 per CU)

typedef __attribute__((ext_vector_type(8))) short bf16x8;
typedef __attribute__((ext_vector_type(4))) float f32x4;

__device__ __forceinline__ float bf2f(unsigned short u) {
  union { unsigned int i; float f; } v; v.i = ((unsigned int)u) << 16; return v.f;
}
__device__ __forceinline__ unsigned short f2bf(float f) {
  union { unsigned int i; float f; } v; v.f = f;
  unsigned int r = v.i + 0x7FFFu + ((v.i >> 16) & 1u);
  return (unsigned short)(r >> 16);
}
__device__ __forceinline__ unsigned int pk_bf16(float a, float b) {
  union { __hip_bfloat162 h; unsigned int u; } cv;
  cv.h = __float22bfloat162_rn(make_float2(a, b));
  return cv.u;
}

// ---------------- workspace layout (bytes); ws_size ~800MB (R3/R6 profile) ---
#define OFF_RP    0u          // row_ptr int32[100001]
#define OFF_W0T   400384u     // W0^T bf16 128x512
#define OFF_W1TP  531456u     // W1'^T bf16 64x128
#define OFF_CVEC  547840u     // fp32[64]
#define OFF_PSUM  548096u     // fp32[SB][128]
#define OFF_PSQ   679168u     // fp32[SB][128]
#define OFF_H     810240u     // h bf16-packed 100000x128
#define END_H     26410240u
#define END_HW    39210240u   // + hw bf16 100000x64

// ---- k_init: [0,RB) row_ptr binsearch | [RB,..) W0 transpose ---------------
__global__ void k_init(const int* __restrict__ row, int* __restrict__ rp,
                       const float* __restrict__ W0, unsigned short* __restrict__ W0t,
                       int n, int e, int RB) {
  int b = blockIdx.x, t = threadIdx.x;
  if (b < RB) {
    int i = b * 256 + t;
    if (i > n) return;
    int lo = 0, hi = e;
    while (lo < hi) { int mid = (lo + hi) >> 1; if (row[mid] < i) lo = mid + 1; else hi = mid; }
    rp[i] = lo;
  } else {
    int idx = (b - RB) * 256 + t;          // 65536 total
    int k = idx & (D_IN - 1);
    int nn = idx >> 9;
    W0t[nn * D_IN + k] = f2bf(W0[k * D_H + nn]);
  }
}

// ---- GEMM1: xw(bf16) = x(fp32) @ W0. tile 128x128, BK=32, dbuf LDS, 1 barrier
__global__ __launch_bounds__(256) void k_gemm1(const float* __restrict__ A,
                                               const unsigned short* __restrict__ Bt,
                                               unsigned short* __restrict__ C, int M) {
  __shared__ unsigned short Ash[2][4096];
  __shared__ unsigned short Bsh[2][4096];
  const int tid = threadIdx.x, lane = tid & 63, wave = tid >> 6;
  const int wm = (wave >> 1) * 64, wn = (wave & 1) * 64;
  const int m0 = blockIdx.x * 128, quad = lane >> 4, l16 = lane & 15;
  f32x4 acc[4][4] = {};
  int am[2], ak[2];
  const float* aptr[2];
  const unsigned short* bptr[2];
#pragma unroll
  for (int i = 0; i < 2; ++i) {
    int c = tid + i * 256;
    am[i] = c >> 2; ak[i] = c & 3;
    int gm = m0 + am[i]; if (gm >= M) gm = M - 1;
    aptr[i] = A + (size_t)gm * D_IN + ak[i] * 8;
    bptr[i] = Bt + (size_t)am[i] * D_IN + ak[i] * 8;
  }
  f32x4 areg[2][2]; bf16x8 breg[2];
#pragma unroll
  for (int i = 0; i < 2; ++i) {
    areg[i][0] = *(const f32x4*)(aptr[i]);
    areg[i][1] = *(const f32x4*)(aptr[i] + 4);
    breg[i]    = *(const bf16x8*)(bptr[i]);
  }
  const int NIT = D_IN / 32;
  for (int it = 0; it < NIT; ++it) {
    const int buf = it & 1;
    unsigned short* ash = Ash[buf];
    unsigned short* bsh = Bsh[buf];
#pragma unroll
    for (int i = 0; i < 2; ++i) {
      unsigned int pk4[4];
      pk4[0] = pk_bf16(areg[i][0][0], areg[i][0][1]);
      pk4[1] = pk_bf16(areg[i][0][2], areg[i][0][3]);
      pk4[2] = pk_bf16(areg[i][1][0], areg[i][1][1]);
      pk4[3] = pk_bf16(areg[i][1][2], areg[i][1][3]);
      *(uint4*)&ash[(ak[i] * 128 + am[i]) * 8] = *(uint4*)pk4;
      *(bf16x8*)&bsh[(ak[i] * 128 + am[i]) * 8] = breg[i];
    }
    __syncthreads();
    if (it + 1 < NIT) {
      int k0 = (it + 1) * 32;
#pragma unroll
      for (int i = 0; i < 2; ++i) {
        areg[i][0] = *(const f32x4*)(aptr[i] + k0);
        areg[i][1] = *(const f32x4*)(aptr[i] + k0 + 4);
        breg[i]    = *(const bf16x8*)(bptr[i] + k0);
      }
    }
    bf16x8 af[4], bfv[4];
#pragma unroll
    for (int mf = 0; mf < 4; ++mf)
      af[mf] = *(const bf16x8*)&ash[(quad * 128 + (wm + mf * 16 + l16)) * 8];
#pragma unroll
    for (int nf = 0; nf < 4; ++nf)
      bfv[nf] = *(const bf16x8*)&bsh[(quad * 128 + (wn + nf * 16 + l16)) * 8];
#pragma unroll
    for (int mf = 0; mf < 4; ++mf)
#pragma unroll
      for (int nf = 0; nf < 4; ++nf)
        acc[mf][nf] = __builtin_amdgcn_mfma_f32_16x16x32_bf16(af[mf], bfv[nf], acc[mf][nf], 0, 0, 0);
  }
  // C/D layout: row = quad*4 + i, col = lane&15 [m89/m91-verified]
#pragma unroll
  for (int mf = 0; mf < 4; ++mf)
#pragma unroll
    for (int nf = 0; nf < 4; ++nf)
#pragma unroll
      for (int i = 0; i < 4; ++i) {
        int r = m0 + wm + mf * 16 + quad * 4 + i;
        int cc = wn + nf * 16 + l16;
        if (r < M) C[(size_t)r * D_H + cc] = f2bf(acc[mf][nf][i]);
      }
}

// accumulate one uint4 (4 packed bf16 pairs) with weight W into a0..a7
#define ACCP(P, W) { \
  union { unsigned int u; float f; } _t; \
  _t.u = (P).x << 16;         a0 += (W) * _t.f; \
  _t.u = (P).x & 0xFFFF0000u; a1 += (W) * _t.f; \
  _t.u = (P).y << 16;         a2 += (W) * _t.f; \
  _t.u = (P).y & 0xFFFF0000u; a3 += (W) * _t.f; \
  _t.u = (P).z << 16;         a4 += (W) * _t.f; \
  _t.u = (P).z & 0xFFFF0000u; a5 += (W) * _t.f; \
  _t.u = (P).w << 16;         a6 += (W) * _t.f; \
  _t.u = (P).w & 0xFFFF0000u; a7 += (W) * _t.f; }

// ---- SpMM1: h = relu(adj @ xw + b0); one wave/node.
// Wave = 4 groups x 16 lanes; each lane gathers dwordx4 (16B) of its group's
// edge row -> ONE gather instruction fetches 4 rows (1KiB, 16 lines) instead
// of one 256B row. 4x fewer gather instructions for identical bytes (MLP /
// VMEM-queue theory). Partials reduced across groups via 2 shfl_xor rounds.
__global__ __launch_bounds__(256) void k_spmm1(const unsigned int* __restrict__ xw2,
                                               const float* __restrict__ adj,
                                               const int* __restrict__ col,
                                               const int* __restrict__ rp,
                                               const float* __restrict__ b0,
                                               unsigned int* __restrict__ h2, int n) {
  int node = blockIdx.x * 4 + (threadIdx.x >> 6);
  if (node >= n) return;
  const int l = threadIdx.x & 63;
  const int q = l >> 4, s = l & 15;   // group, 16B slice (uints 4s..4s+3)
  const int e0 = rp[node], e1 = rp[node + 1];
  float a0 = 0.f, a1 = 0.f, a2 = 0.f, a3 = 0.f;
  float a4 = 0.f, a5 = 0.f, a6 = 0.f, a7 = 0.f;
  int e = e0;
  // main: 16 edges / iter, group q owns edges eb..eb+3 -> 4 gather insts
  for (; e + 16 <= e1; e += 16) {
    int eb = e + 4 * q;
    int   c0 = col[eb],     c1 = col[eb + 1], c2 = col[eb + 2], c3 = col[eb + 3];
    float w0 = adj[eb],     w1 = adj[eb + 1], w2 = adj[eb + 2], w3 = adj[eb + 3];
    uint4 p0 = *(const uint4*)(xw2 + (size_t)c0 * 64 + 4 * s);
    uint4 p1 = *(const uint4*)(xw2 + (size_t)c1 * 64 + 4 * s);
    uint4 p2 = *(const uint4*)(xw2 + (size_t)c2 * 64 + 4 * s);
    uint4 p3 = *(const uint4*)(xw2 + (size_t)c3 * 64 + 4 * s);
    ACCP(p0, w0); ACCP(p1, w1); ACCP(p2, w2); ACCP(p3, w3);
  }
  // tail: 4 edges / iter (1 gather inst), clamped + zero-weighted
  for (; e < e1; e += 4) {
    int idx = e + q;
    int ic = idx < e1 ? idx : e1 - 1;
    int   c = col[ic];
    float w = idx < e1 ? adj[ic] : 0.f;
    uint4 p = *(const uint4*)(xw2 + (size_t)c * 64 + 4 * s);
    ACCP(p, w);
  }
  // combine the 4 group partials (lanes s, s+16, s+32, s+48)
#define RED2(v) { v += __shfl_xor(v, 16, 64); v += __shfl_xor(v, 32, 64); }
  RED2(a0) RED2(a1) RED2(a2) RED2(a3) RED2(a4) RED2(a5) RED2(a6) RED2(a7)
#undef RED2
  if (q == 0) {   // lanes 0..15 write 16B each = 256B row
    float4 bl = *(const float4*)(b0 + 8 * s);
    float4 bh = *(const float4*)(b0 + 8 * s + 4);
    float r0 = fmaxf(a0 + bl.x, 0.f), r1 = fmaxf(a1 + bl.y, 0.f);
    float r2 = fmaxf(a2 + bl.z, 0.f), r3 = fmaxf(a3 + bl.w, 0.f);
    float r4 = fmaxf(a4 + bh.x, 0.f), r5 = fmaxf(a5 + bh.y, 0.f);
    float r6 = fmaxf(a6 + bh.z, 0.f), r7 = fmaxf(a7 + bh.w, 0.f);
    uint4 o;
    o.x = ((unsigned int)f2bf(r1) << 16) | (unsigned int)f2bf(r0);
    o.y = ((unsigned int)f2bf(r3) << 16) | (unsigned int)f2bf(r2);
    o.z = ((unsigned int)f2bf(r5) << 16) | (unsigned int)f2bf(r4);
    o.w = ((unsigned int)f2bf(r7) << 16) | (unsigned int)f2bf(r6);
    *(uint4*)(h2 + (size_t)node * 64 + 4 * s) = o;
  }
}

// ---- BN stats: SB=256 per-block partials (no atomics) -----------------------
__global__ __launch_bounds__(256) void k_stats(const unsigned int* __restrict__ h2,
                                               float* __restrict__ psum,
                                               float* __restrict__ psq, int n) {
  __shared__ float sA[256], sB[256], qA[256], qB[256];
  int t = threadIdx.x;
  int f2 = t & 63, rg = t >> 6;
  float s0 = 0.f, s1 = 0.f, q0 = 0.f, q1 = 0.f;
  for (int r = blockIdx.x * 4 + rg; r < n; r += gridDim.x * 4) {
    unsigned int p = h2[(size_t)r * 64 + f2];
    float v0 = bf2f((unsigned short)(p & 0xFFFF));
    float v1 = bf2f((unsigned short)(p >> 16));
    s0 += v0; s1 += v1; q0 += v0 * v0; q1 += v1 * v1;
  }
  sA[t] = s0; sB[t] = s1; qA[t] = q0; qB[t] = q1;
  __syncthreads();
  if (t < 64) {
    float S0 = sA[t] + sA[t + 64] + sA[t + 128] + sA[t + 192];
    float S1 = sB[t] + sB[t + 64] + sB[t + 128] + sB[t + 192];
    float Q0 = qA[t] + qA[t + 64] + qA[t + 128] + qA[t + 192];
    float Q1 = qB[t] + qB[t + 64] + qB[t + 128] + qB[t + 192];
    psum[blockIdx.x * 128 + 2 * t]     = S0;
    psum[blockIdx.x * 128 + 2 * t + 1] = S1;
    psq [blockIdx.x * 128 + 2 * t]     = Q0;
    psq [blockIdx.x * 128 + 2 * t + 1] = Q1;
  }
}

// ---- prep2: PARALLEL partial reduce -> mean/istd -> W1', cvec ---------------
__global__ void k_prep2(const float* __restrict__ psum, const float* __restrict__ psq,
                        const float* __restrict__ W1,
                        unsigned short* __restrict__ W1tp, float* __restrict__ cvec, int n) {
  __shared__ float rs[256], rq[256];
  __shared__ float mean_s[128], istd_s[128];
  __shared__ float cpart[256];
  int t = threadIdx.x;            // 256
  int f = t & 127, half = t >> 7; // each (f,half) sums SB/2 blocks
  {
    float s = 0.f, q = 0.f;
#pragma unroll 8
    for (int b = half * (SB / 2); b < (half + 1) * (SB / 2); ++b) {
      s += psum[b * 128 + f]; q += psq[b * 128 + f];
    }
    rs[t] = s; rq[t] = q;
  }
  __syncthreads();
  if (t < 128) {
    float s = rs[t] + rs[t + 128];
    float q = rq[t] + rq[t + 128];
    float m = s / (float)n;
    float var = q / (float)n - m * m;
    if (var < 0.f) var = 0.f;
    mean_s[t] = m;
    istd_s[t] = rsqrtf(var + 1e-5f);
  }
  __syncthreads();
  for (int idx = t; idx < D_OUT * D_H; idx += 256) {
    int nn = idx >> 7, k = idx & 127;
    W1tp[nn * D_H + k] = f2bf(istd_s[k] * W1[k * D_OUT + nn]);
  }
  {  // cvec: 4 partials per output column
    int o = t & 63, part = t >> 6;
    float a = 0.f;
    for (int k = part * 32; k < part * 32 + 32; ++k)
      a += mean_s[k] * istd_s[k] * W1[k * D_OUT + o];
    cpart[t] = a;
  }
  __syncthreads();
  if (t < D_OUT)
    cvec[t] = -(cpart[t] + cpart[t + 64] + cpart[t + 128] + cpart[t + 192]);
}

// ---- GEMM2: hw(bf16) = h(bf16) @ W1' + c. tile 128x64, BK=32 ----------------
__global__ __launch_bounds__(256) void k_gemm2(const unsigned short* __restrict__ A,
                                               const unsigned short* __restrict__ Bt,
                                               const float* __restrict__ cvec,
                                               unsigned short* __restrict__ Cout, int M) {
  __shared__ unsigned short Ash[4096];
  __shared__ unsigned short Bsh[2048];
  const int tid = threadIdx.x, lane = tid & 63, wave = tid >> 6;
  const int wm = wave * 32, m0 = blockIdx.x * 128;
  const int quad = lane >> 4, l16 = lane & 15;
  f32x4 acc[2][4] = {};
  for (int k0 = 0; k0 < D_H; k0 += 32) {
    __syncthreads();
#pragma unroll
    for (int i = 0; i < 2; ++i) {
      int c = tid + i * 256;
      int m = c >> 2, k8 = c & 3;
      int gm = m0 + m; if (gm >= M) gm = M - 1;
      *(bf16x8*)&Ash[(k8 * 128 + m) * 8] = *(const bf16x8*)&A[(size_t)gm * D_H + k0 + k8 * 8];
    }
    {
      int nn = tid >> 2, k8 = tid & 3;
      *(bf16x8*)&Bsh[(k8 * 64 + nn) * 8] = *(const bf16x8*)&Bt[(size_t)nn * D_H + k0 + k8 * 8];
    }
    __syncthreads();
    bf16x8 af[2], bfv[4];
#pragma unroll
    for (int mf = 0; mf < 2; ++mf)
      af[mf] = *(const bf16x8*)&Ash[(quad * 128 + (wm + mf * 16 + l16)) * 8];
#pragma unroll
    for (int nf = 0; nf < 4; ++nf)
      bfv[nf] = *(const bf16x8*)&Bsh[(quad * 64 + (nf * 16 + l16)) * 8];
#pragma unroll
    for (int mf = 0; mf < 2; ++mf)
#pragma unroll
      for (int nf = 0; nf < 4; ++nf)
        acc[mf][nf] = __builtin_amdgcn_mfma_f32_16x16x32_bf16(af[mf], bfv[nf], acc[mf][nf], 0, 0, 0);
  }
#pragma unroll
  for (int mf = 0; mf < 2; ++mf)
#pragma unroll
    for (int nf = 0; nf < 4; ++nf)
#pragma unroll
      for (int i = 0; i < 4; ++i) {
        int r = m0 + wm + mf * 16 + quad * 4 + i;
        int cc = nf * 16 + l16;
        if (r < M) Cout[(size_t)r * 64 + cc] = f2bf(acc[mf][nf][i] + cvec[cc]);
      }
}

// ---- SpMM2: out(fp32) = adj @ hw + b1; one wave/node.
// 8 groups x 8 lanes; lane gathers dwordx4 of its group's edge row -> ONE
// instruction fetches 8 rows (1KiB). 8x fewer gather insts. 3 shfl_xor rounds.
__global__ __launch_bounds__(256) void k_spmm2(const unsigned int* __restrict__ hw2,
                                               const float* __restrict__ adj,
                                               const int* __restrict__ col,
                                               const int* __restrict__ rp,
                                               const float* __restrict__ b1,
                                               float* __restrict__ outp, int n) {
  int node = blockIdx.x * 4 + (threadIdx.x >> 6);
  if (node >= n) return;
  const int l = threadIdx.x & 63;
  const int g = l >> 3, s = l & 7;   // group, 16B slice (uints 4s..4s+3)
  const int e0 = rp[node], e1 = rp[node + 1];
  float a0 = 0.f, a1 = 0.f, a2 = 0.f, a3 = 0.f;
  float a4 = 0.f, a5 = 0.f, a6 = 0.f, a7 = 0.f;
  int e = e0;
  // main: 16 edges / iter, group g owns edges eb..eb+1 -> 2 gather insts
  for (; e + 16 <= e1; e += 16) {
    int eb = e + 2 * g;
    int   c0 = col[eb],  c1 = col[eb + 1];
    float w0 = adj[eb],  w1 = adj[eb + 1];
    uint4 p0 = *(const uint4*)(hw2 + (size_t)c0 * 32 + 4 * s);
    uint4 p1 = *(const uint4*)(hw2 + (size_t)c1 * 32 + 4 * s);
    ACCP(p0, w0); ACCP(p1, w1);
  }
  // tail: 8 edges / iter (1 gather inst)
  for (; e < e1; e += 8) {
    int idx = e + g;
    int ic = idx < e1 ? idx : e1 - 1;
    int   c = col[ic];
    float w = idx < e1 ? adj[ic] : 0.f;
    uint4 p = *(const uint4*)(hw2 + (size_t)c * 32 + 4 * s);
    ACCP(p, w);
  }
#define RED3(v) { v += __shfl_xor(v, 8, 64); v += __shfl_xor(v, 16, 64); v += __shfl_xor(v, 32, 64); }
  RED3(a0) RED3(a1) RED3(a2) RED3(a3) RED3(a4) RED3(a5) RED3(a6) RED3(a7)
#undef RED3
  if (g == 0) {  // lanes 0..7 write 32B each = 256B row (fp32 out)
    float4 bl = *(const float4*)(b1 + 8 * s);
    float4 bh = *(const float4*)(b1 + 8 * s + 4);
    float4 r0, r1;
    r0.x = a0 + bl.x; r0.y = a1 + bl.y; r0.z = a2 + bl.z; r0.w = a3 + bl.w;
    r1.x = a4 + bh.x; r1.y = a5 + bh.y; r1.z = a6 + bh.z; r1.w = a7 + bh.w;
    *(float4*)(outp + (size_t)node * 64 + 8 * s)     = r0;
    *(float4*)(outp + (size_t)node * 64 + 8 * s + 4) = r1;
  }
}

extern "C" void kernel_launch(void* const* d_in, const int* in_sizes, int n_in,
                              void* d_out, int out_size, void* d_ws, size_t ws_size,
                              hipStream_t stream) {
  const float* x   = (const float*)d_in[0];
  const float* W0  = (const float*)d_in[1];
  const float* b0  = (const float*)d_in[2];
  const float* W1  = (const float*)d_in[3];
  const float* b1  = (const float*)d_in[4];
  const float* adj = (const float*)d_in[5];
  const int* row = (const int*)d_in[6];
  const int* col = (const int*)d_in[7];
  const int N = in_sizes[0] / D_IN;
  const int E = in_sizes[5];

  char* ws = (char*)d_ws;
  int*            rp   = (int*)(ws + OFF_RP);
  unsigned short* W0t  = (unsigned short*)(ws + OFF_W0T);
  unsigned short* W1tp = (unsigned short*)(ws + OFF_W1TP);
  float*          cvec = (float*)(ws + OFF_CVEC);
  float*          psum = (float*)(ws + OFF_PSUM);
  float*          psq  = (float*)(ws + OFF_PSQ);
  unsigned short* h    = (unsigned short*)(ws + OFF_H);

  // xw (packed bf16 100000x128 = 25.6MB) overlays d_out (fp32 out = 25.6MB).
  unsigned short* xw = (unsigned short*)d_out;
  const bool hw_in_ws = (ws_size >= (size_t)END_HW);
  unsigned short* hwp  = hw_in_ws ? (unsigned short*)(ws + END_H) : (unsigned short*)d_out;
  float*          outd = hw_in_ws ? (float*)d_out                 : (float*)(ws + OFF_H);

  const int RB = (N + 1 + 255) / 256;
  const int TB = (D_IN * D_H) / 256;
  k_init<<<RB + TB, 256, 0, stream>>>(row, rp, W0, W0t, N, E, RB);
  k_gemm1<<<(N + 127) / 128, 256, 0, stream>>>(x, W0t, xw, N);
  k_spmm1<<<(N + 3) / 4, 256, 0, stream>>>((const unsigned int*)xw, adj, col, rp, b0,
                                           (unsigned int*)h, N);
  k_stats<<<SB, 256, 0, stream>>>((const unsigned int*)h, psum, psq, N);
  k_prep2<<<1, 256, 0, stream>>>(psum, psq, W1, W1tp, cvec, N);
  k_gemm2<<<(N + 127) / 128, 256, 0, stream>>>(h, W1tp, cvec, hwp, N);
  k_spmm2<<<(N + 3) / 4, 256, 0, stream>>>((const unsigned int*)hwp, adj, col, rp, b1,
                                           outd, N);
  if (!hw_in_ws) {
    hipMemcpyAsync(d_out, outd, (size_t)N * D_OUT * sizeof(float),
                   hipMemcpyDeviceToDevice, stream);
  }
}

// Round 3
// 465.565 us; speedup vs baseline: 1.0566x; 1.0566x over previous
//
#include <hip/hip_runtime.h>
#include <hip/hip_bf16.h>
#include <cstdint>
#include <cstddef>

#define D_IN  512
#define D_H   128
#define D_OUT 64
#define SB    64    // stats partial slots (atomic spread)

typedef __attribute__((ext_vector_type(8))) short bf16x8;
typedef __attribute__((ext_vector_type(4))) float f32x4;

__device__ __forceinline__ float bf2f(unsigned short u) {
  union { unsigned int i; float f; } v; v.i = ((unsigned int)u) << 16; return v.f;
}
__device__ __forceinline__ unsigned short f2bf(float f) {
  union { unsigned int i; float f; } v; v.f = f;
  unsigned int r = v.i + 0x7FFFu + ((v.i >> 16) & 1u);
  return (unsigned short)(r >> 16);
}
__device__ __forceinline__ unsigned int pk_bf16(float a, float b) {
  union { __hip_bfloat162 h; unsigned int u; } cv;
  cv.h = __float22bfloat162_rn(make_float2(a, b));
  return cv.u;
}

// ---------------- workspace layout (bytes); ws_size ~800MB -------------------
#define OFF_RP    0u          // row_ptr int32[100001]
#define OFF_W0T   400384u     // W0^T bf16 128x512
#define OFF_W1TP  531456u     // W1'^T bf16 64x128
#define OFF_CVEC  547840u     // fp32[64]
#define OFF_PSUM  548096u     // fp32[SB][128] (32KB used)
#define OFF_PSQ   679168u     // fp32[SB][128] (32KB used)
#define OFF_H     810240u     // h bf16-packed 100000x128
#define END_H     26410240u
#define END_HW    39210240u   // + hw bf16 100000x64
#define OFF_XW    39210240u   // xw bf16-packed 100000x128 (moved out of d_out)
#define END_XW    64810240u

// ---- k_init: [0,RB) row_ptr binsearch | [RB,RB+TB) W0 transpose | last: zero
__global__ void k_init(const int* __restrict__ row, int* __restrict__ rp,
                       const float* __restrict__ W0, unsigned short* __restrict__ W0t,
                       float* __restrict__ psum, float* __restrict__ psq,
                       int n, int e, int RB, int TB) {
  int b = blockIdx.x, t = threadIdx.x;
  if (b < RB) {
    int i = b * 256 + t;
    if (i > n) return;
    int lo = 0, hi = e;
    while (lo < hi) { int mid = (lo + hi) >> 1; if (row[mid] < i) lo = mid + 1; else hi = mid; }
    rp[i] = lo;
  } else if (b < RB + TB) {
    int idx = (b - RB) * 256 + t;          // 65536 total
    int k = idx & (D_IN - 1);
    int nn = idx >> 9;
    W0t[nn * D_IN + k] = f2bf(W0[k * D_H + nn]);
  } else {
    for (int i = t; i < SB * 128; i += 256) { psum[i] = 0.f; psq[i] = 0.f; }
  }
}

// ---- GEMM1: xw(bf16) = x(fp32) @ W0. tile 128x128, BK=32, dbuf LDS, 1 barrier
__global__ __launch_bounds__(256) void k_gemm1(const float* __restrict__ A,
                                               const unsigned short* __restrict__ Bt,
                                               unsigned short* __restrict__ C, int M) {
  __shared__ unsigned short Ash[2][4096];
  __shared__ unsigned short Bsh[2][4096];
  const int tid = threadIdx.x, lane = tid & 63, wave = tid >> 6;
  const int wm = (wave >> 1) * 64, wn = (wave & 1) * 64;
  const int m0 = blockIdx.x * 128, quad = lane >> 4, l16 = lane & 15;
  f32x4 acc[4][4] = {};
  int am[2], ak[2];
  const float* aptr[2];
  const unsigned short* bptr[2];
#pragma unroll
  for (int i = 0; i < 2; ++i) {
    int c = tid + i * 256;
    am[i] = c >> 2; ak[i] = c & 3;
    int gm = m0 + am[i]; if (gm >= M) gm = M - 1;
    aptr[i] = A + (size_t)gm * D_IN + ak[i] * 8;
    bptr[i] = Bt + (size_t)am[i] * D_IN + ak[i] * 8;
  }
  f32x4 areg[2][2]; bf16x8 breg[2];
#pragma unroll
  for (int i = 0; i < 2; ++i) {
    areg[i][0] = *(const f32x4*)(aptr[i]);
    areg[i][1] = *(const f32x4*)(aptr[i] + 4);
    breg[i]    = *(const bf16x8*)(bptr[i]);
  }
  const int NIT = D_IN / 32;
  for (int it = 0; it < NIT; ++it) {
    const int buf = it & 1;
    unsigned short* ash = Ash[buf];
    unsigned short* bsh = Bsh[buf];
#pragma unroll
    for (int i = 0; i < 2; ++i) {
      unsigned int pk4[4];
      pk4[0] = pk_bf16(areg[i][0][0], areg[i][0][1]);
      pk4[1] = pk_bf16(areg[i][0][2], areg[i][0][3]);
      pk4[2] = pk_bf16(areg[i][1][0], areg[i][1][1]);
      pk4[3] = pk_bf16(areg[i][1][2], areg[i][1][3]);
      *(uint4*)&ash[(ak[i] * 128 + am[i]) * 8] = *(uint4*)pk4;
      *(bf16x8*)&bsh[(ak[i] * 128 + am[i]) * 8] = breg[i];
    }
    __syncthreads();
    if (it + 1 < NIT) {
      int k0 = (it + 1) * 32;
#pragma unroll
      for (int i = 0; i < 2; ++i) {
        areg[i][0] = *(const f32x4*)(aptr[i] + k0);
        areg[i][1] = *(const f32x4*)(aptr[i] + k0 + 4);
        breg[i]    = *(const bf16x8*)(bptr[i] + k0);
      }
    }
    bf16x8 af[4], bfv[4];
#pragma unroll
    for (int mf = 0; mf < 4; ++mf)
      af[mf] = *(const bf16x8*)&ash[(quad * 128 + (wm + mf * 16 + l16)) * 8];
#pragma unroll
    for (int nf = 0; nf < 4; ++nf)
      bfv[nf] = *(const bf16x8*)&bsh[(quad * 128 + (wn + nf * 16 + l16)) * 8];
#pragma unroll
    for (int mf = 0; mf < 4; ++mf)
#pragma unroll
      for (int nf = 0; nf < 4; ++nf)
        acc[mf][nf] = __builtin_amdgcn_mfma_f32_16x16x32_bf16(af[mf], bfv[nf], acc[mf][nf], 0, 0, 0);
  }
  // C/D layout: row = quad*4 + i, col = lane&15 [m89/m91-verified]
#pragma unroll
  for (int mf = 0; mf < 4; ++mf)
#pragma unroll
    for (int nf = 0; nf < 4; ++nf)
#pragma unroll
      for (int i = 0; i < 4; ++i) {
        int r = m0 + wm + mf * 16 + quad * 4 + i;
        int cc = wn + nf * 16 + l16;
        if (r < M) C[(size_t)r * D_H + cc] = f2bf(acc[mf][nf][i]);
      }
}

// accumulate one uint4 (4 packed bf16 pairs) with weight W into a0..a7
#define ACCP(P, W) { \
  union { unsigned int u; float f; } _t; \
  _t.u = (P).x << 16;         a0 += (W) * _t.f; \
  _t.u = (P).x & 0xFFFF0000u; a1 += (W) * _t.f; \
  _t.u = (P).y << 16;         a2 += (W) * _t.f; \
  _t.u = (P).y & 0xFFFF0000u; a3 += (W) * _t.f; \
  _t.u = (P).z << 16;         a4 += (W) * _t.f; \
  _t.u = (P).z & 0xFFFF0000u; a5 += (W) * _t.f; \
  _t.u = (P).w << 16;         a6 += (W) * _t.f; \
  _t.u = (P).w & 0xFFFF0000u; a7 += (W) * _t.f; }

// ---- SpMM1 + fused BN stats: h = relu(adj @ xw + b0); one wave/node.
// Gather: 4x16-lane groups, dwordx4/lane (1KiB = 4 rows per instruction).
// Epilogue: per-wave LDS slice of (sum, sumsq), block-reduce, 64-slot
// spread fp32 atomics into psum/psq (zeroed by k_init).
__global__ __launch_bounds__(256) void k_spmm1(const unsigned int* __restrict__ xw2,
                                               const float* __restrict__ adj,
                                               const int* __restrict__ col,
                                               const int* __restrict__ rp,
                                               const float* __restrict__ b0,
                                               unsigned int* __restrict__ h2,
                                               float* __restrict__ psum,
                                               float* __restrict__ psq, int n) {
  __shared__ float sst[512], sqt[512];   // [wave][128]
  const int t = threadIdx.x;
  const int wave = t >> 6, l = t & 63;
  // each wave zeroes its own slice (2 floats/thread) - no barrier needed
  sst[wave * 128 + l] = 0.f; sst[wave * 128 + 64 + l] = 0.f;
  sqt[wave * 128 + l] = 0.f; sqt[wave * 128 + 64 + l] = 0.f;
  const int node = blockIdx.x * 4 + wave;
  const int q = l >> 4, s = l & 15;   // group, 16B slice (uints 4s..4s+3)
  if (node < n) {
    const int e0 = rp[node], e1 = rp[node + 1];
    float a0 = 0.f, a1 = 0.f, a2 = 0.f, a3 = 0.f;
    float a4 = 0.f, a5 = 0.f, a6 = 0.f, a7 = 0.f;
    int e = e0;
    for (; e + 16 <= e1; e += 16) {      // group q owns edges eb..eb+3
      int eb = e + 4 * q;
      int   c0 = col[eb],     c1 = col[eb + 1], c2 = col[eb + 2], c3 = col[eb + 3];
      float w0 = adj[eb],     w1 = adj[eb + 1], w2 = adj[eb + 2], w3 = adj[eb + 3];
      uint4 p0 = *(const uint4*)(xw2 + (size_t)c0 * 64 + 4 * s);
      uint4 p1 = *(const uint4*)(xw2 + (size_t)c1 * 64 + 4 * s);
      uint4 p2 = *(const uint4*)(xw2 + (size_t)c2 * 64 + 4 * s);
      uint4 p3 = *(const uint4*)(xw2 + (size_t)c3 * 64 + 4 * s);
      ACCP(p0, w0); ACCP(p1, w1); ACCP(p2, w2); ACCP(p3, w3);
    }
    for (; e < e1; e += 4) {             // tail: 4 edges / round
      int idx = e + q;
      int ic = idx < e1 ? idx : e1 - 1;
      int   c = col[ic];
      float w = idx < e1 ? adj[ic] : 0.f;
      uint4 p = *(const uint4*)(xw2 + (size_t)c * 64 + 4 * s);
      ACCP(p, w);
    }
#define RED2(v) { v += __shfl_xor(v, 16, 64); v += __shfl_xor(v, 32, 64); }
    RED2(a0) RED2(a1) RED2(a2) RED2(a3) RED2(a4) RED2(a5) RED2(a6) RED2(a7)
#undef RED2
    if (q == 0) {   // lanes 0..15 own features 8s..8s+7
      float4 bl = *(const float4*)(b0 + 8 * s);
      float4 bh = *(const float4*)(b0 + 8 * s + 4);
      float r0 = fmaxf(a0 + bl.x, 0.f), r1 = fmaxf(a1 + bl.y, 0.f);
      float r2 = fmaxf(a2 + bl.z, 0.f), r3 = fmaxf(a3 + bl.w, 0.f);
      float r4 = fmaxf(a4 + bh.x, 0.f), r5 = fmaxf(a5 + bh.y, 0.f);
      float r6 = fmaxf(a6 + bh.z, 0.f), r7 = fmaxf(a7 + bh.w, 0.f);
      uint4 o;
      o.x = ((unsigned int)f2bf(r1) << 16) | (unsigned int)f2bf(r0);
      o.y = ((unsigned int)f2bf(r3) << 16) | (unsigned int)f2bf(r2);
      o.z = ((unsigned int)f2bf(r5) << 16) | (unsigned int)f2bf(r4);
      o.w = ((unsigned int)f2bf(r7) << 16) | (unsigned int)f2bf(r6);
      *(uint4*)(h2 + (size_t)node * 64 + 4 * s) = o;
      float* sw = sst + wave * 128 + 8 * s;
      float* qw = sqt + wave * 128 + 8 * s;
      sw[0] = r0; sw[1] = r1; sw[2] = r2; sw[3] = r3;
      sw[4] = r4; sw[5] = r5; sw[6] = r6; sw[7] = r7;
      qw[0] = r0 * r0; qw[1] = r1 * r1; qw[2] = r2 * r2; qw[3] = r3 * r3;
      qw[4] = r4 * r4; qw[5] = r5 * r5; qw[6] = r6 * r6; qw[7] = r7 * r7;
    }
  }
  __syncthreads();
  if (t < 128) {
    float S = sst[t] + sst[128 + t] + sst[256 + t] + sst[384 + t];
    float Q = sqt[t] + sqt[128 + t] + sqt[256 + t] + sqt[384 + t];
    int slot = (blockIdx.x & (SB - 1)) * 128 + t;
    atomicAdd(&psum[slot], S);
    atomicAdd(&psq[slot], Q);
  }
}

// ---- prep2: reduce SB=64 slot partials -> mean/istd -> W1', cvec ------------
__global__ void k_prep2(const float* __restrict__ psum, const float* __restrict__ psq,
                        const float* __restrict__ W1,
                        unsigned short* __restrict__ W1tp, float* __restrict__ cvec, int n) {
  __shared__ float rs[256], rq[256];
  __shared__ float mean_s[128], istd_s[128];
  __shared__ float cpart[256];
  int t = threadIdx.x;            // 256
  int f = t & 127, half = t >> 7; // each (f,half) sums SB/2 slots
  {
    float s = 0.f, q = 0.f;
#pragma unroll 8
    for (int b = half * (SB / 2); b < (half + 1) * (SB / 2); ++b) {
      s += psum[b * 128 + f]; q += psq[b * 128 + f];
    }
    rs[t] = s; rq[t] = q;
  }
  __syncthreads();
  if (t < 128) {
    float s = rs[t] + rs[t + 128];
    float q = rq[t] + rq[t + 128];
    float m = s / (float)n;
    float var = q / (float)n - m * m;
    if (var < 0.f) var = 0.f;
    mean_s[t] = m;
    istd_s[t] = rsqrtf(var + 1e-5f);
  }
  __syncthreads();
  for (int idx = t; idx < D_OUT * D_H; idx += 256) {
    int nn = idx >> 7, k = idx & 127;
    W1tp[nn * D_H + k] = f2bf(istd_s[k] * W1[k * D_OUT + nn]);
  }
  {  // cvec: 4 partials per output column
    int o = t & 63, part = t >> 6;
    float a = 0.f;
    for (int k = part * 32; k < part * 32 + 32; ++k)
      a += mean_s[k] * istd_s[k] * W1[k * D_OUT + o];
    cpart[t] = a;
  }
  __syncthreads();
  if (t < D_OUT)
    cvec[t] = -(cpart[t] + cpart[t + 64] + cpart[t + 128] + cpart[t + 192]);
}

// ---- GEMM2: hw(bf16) = h(bf16) @ W1' + c. tile 128x64, BK=32 ----------------
__global__ __launch_bounds__(256) void k_gemm2(const unsigned short* __restrict__ A,
                                               const unsigned short* __restrict__ Bt,
                                               const float* __restrict__ cvec,
                                               unsigned short* __restrict__ Cout, int M) {
  __shared__ unsigned short Ash[4096];
  __shared__ unsigned short Bsh[2048];
  const int tid = threadIdx.x, lane = tid & 63, wave = tid >> 6;
  const int wm = wave * 32, m0 = blockIdx.x * 128;
  const int quad = lane >> 4, l16 = lane & 15;
  f32x4 acc[2][4] = {};
  for (int k0 = 0; k0 < D_H; k0 += 32) {
    __syncthreads();
#pragma unroll
    for (int i = 0; i < 2; ++i) {
      int c = tid + i * 256;
      int m = c >> 2, k8 = c & 3;
      int gm = m0 + m; if (gm >= M) gm = M - 1;
      *(bf16x8*)&Ash[(k8 * 128 + m) * 8] = *(const bf16x8*)&A[(size_t)gm * D_H + k0 + k8 * 8];
    }
    {
      int nn = tid >> 2, k8 = tid & 3;
      *(bf16x8*)&Bsh[(k8 * 64 + nn) * 8] = *(const bf16x8*)&Bt[(size_t)nn * D_H + k0 + k8 * 8];
    }
    __syncthreads();
    bf16x8 af[2], bfv[4];
#pragma unroll
    for (int mf = 0; mf < 2; ++mf)
      af[mf] = *(const bf16x8*)&Ash[(quad * 128 + (wm + mf * 16 + l16)) * 8];
#pragma unroll
    for (int nf = 0; nf < 4; ++nf)
      bfv[nf] = *(const bf16x8*)&Bsh[(quad * 64 + (nf * 16 + l16)) * 8];
#pragma unroll
    for (int mf = 0; mf < 2; ++mf)
#pragma unroll
      for (int nf = 0; nf < 4; ++nf)
        acc[mf][nf] = __builtin_amdgcn_mfma_f32_16x16x32_bf16(af[mf], bfv[nf], acc[mf][nf], 0, 0, 0);
  }
#pragma unroll
  for (int mf = 0; mf < 2; ++mf)
#pragma unroll
    for (int nf = 0; nf < 4; ++nf)
#pragma unroll
      for (int i = 0; i < 4; ++i) {
        int r = m0 + wm + mf * 16 + quad * 4 + i;
        int cc = nf * 16 + l16;
        if (r < M) Cout[(size_t)r * 64 + cc] = f2bf(acc[mf][nf][i] + cvec[cc]);
      }
}

// ---- SpMM2: out(fp32) = adj @ hw + b1; one wave/node, 8x8-lane groups -------
__global__ __launch_bounds__(256) void k_spmm2(const unsigned int* __restrict__ hw2,
                                               const float* __restrict__ adj,
                                               const int* __restrict__ col,
                                               const int* __restrict__ rp,
                                               const float* __restrict__ b1,
                                               float* __restrict__ outp, int n) {
  int node = blockIdx.x * 4 + (threadIdx.x >> 6);
  if (node >= n) return;
  const int l = threadIdx.x & 63;
  const int g = l >> 3, s = l & 7;   // group, 16B slice (uints 4s..4s+3)
  const int e0 = rp[node], e1 = rp[node + 1];
  float a0 = 0.f, a1 = 0.f, a2 = 0.f, a3 = 0.f;
  float a4 = 0.f, a5 = 0.f, a6 = 0.f, a7 = 0.f;
  int e = e0;
  for (; e + 16 <= e1; e += 16) {      // group g owns edges eb..eb+1
    int eb = e + 2 * g;
    int   c0 = col[eb],  c1 = col[eb + 1];
    float w0 = adj[eb],  w1 = adj[eb + 1];
    uint4 p0 = *(const uint4*)(hw2 + (size_t)c0 * 32 + 4 * s);
    uint4 p1 = *(const uint4*)(hw2 + (size_t)c1 * 32 + 4 * s);
    ACCP(p0, w0); ACCP(p1, w1);
  }
  for (; e < e1; e += 8) {             // tail: 8 edges / round
    int idx = e + g;
    int ic = idx < e1 ? idx : e1 - 1;
    int   c = col[ic];
    float w = idx < e1 ? adj[ic] : 0.f;
    uint4 p = *(const uint4*)(hw2 + (size_t)c * 32 + 4 * s);
    ACCP(p, w);
  }
#define RED3(v) { v += __shfl_xor(v, 8, 64); v += __shfl_xor(v, 16, 64); v += __shfl_xor(v, 32, 64); }
  RED3(a0) RED3(a1) RED3(a2) RED3(a3) RED3(a4) RED3(a5) RED3(a6) RED3(a7)
#undef RED3
  if (g == 0) {  // lanes 0..7 write 32B each = 256B row (fp32 out)
    float4 bl = *(const float4*)(b1 + 8 * s);
    float4 bh = *(const float4*)(b1 + 8 * s + 4);
    float4 r0, r1;
    r0.x = a0 + bl.x; r0.y = a1 + bl.y; r0.z = a2 + bl.z; r0.w = a3 + bl.w;
    r1.x = a4 + bh.x; r1.y = a5 + bh.y; r1.z = a6 + bh.z; r1.w = a7 + bh.w;
    *(float4*)(outp + (size_t)node * 64 + 8 * s)     = r0;
    *(float4*)(outp + (size_t)node * 64 + 8 * s + 4) = r1;
  }
}

extern "C" void kernel_launch(void* const* d_in, const int* in_sizes, int n_in,
                              void* d_out, int out_size, void* d_ws, size_t ws_size,
                              hipStream_t stream) {
  const float* x   = (const float*)d_in[0];
  const float* W0  = (const float*)d_in[1];
  const float* b0  = (const float*)d_in[2];
  const float* W1  = (const float*)d_in[3];
  const float* b1  = (const float*)d_in[4];
  const float* adj = (const float*)d_in[5];
  const int* row = (const int*)d_in[6];
  const int* col = (const int*)d_in[7];
  const int N = in_sizes[0] / D_IN;
  const int E = in_sizes[5];

  char* ws = (char*)d_ws;
  int*            rp   = (int*)(ws + OFF_RP);
  unsigned short* W0t  = (unsigned short*)(ws + OFF_W0T);
  unsigned short* W1tp = (unsigned short*)(ws + OFF_W1TP);
  float*          cvec = (float*)(ws + OFF_CVEC);
  float*          psum = (float*)(ws + OFF_PSUM);
  float*          psq  = (float*)(ws + OFF_PSQ);
  unsigned short* h    = (unsigned short*)(ws + OFF_H);

  // ws-resident xw/hw when ws is large (normal case); fallback = old overlay.
  const bool big_ws = (ws_size >= (size_t)END_XW);
  unsigned short* xw   = big_ws ? (unsigned short*)(ws + OFF_XW) : (unsigned short*)d_out;
  unsigned short* hwp  = big_ws ? (unsigned short*)(ws + END_H)  : (unsigned short*)d_out;
  float*          outd = (float*)d_out;

  const int RB = (N + 1 + 255) / 256;
  const int TB = (D_IN * D_H) / 256;
  k_init<<<RB + TB + 1, 256, 0, stream>>>(row, rp, W0, W0t, psum, psq, N, E, RB, TB);
  k_gemm1<<<(N + 127) / 128, 256, 0, stream>>>(x, W0t, xw, N);
  k_spmm1<<<(N + 3) / 4, 256, 0, stream>>>((const unsigned int*)xw, adj, col, rp, b0,
                                           (unsigned int*)h, psum, psq, N);
  k_prep2<<<1, 256, 0, stream>>>(psum, psq, W1, W1tp, cvec, N);
  k_gemm2<<<(N + 127) / 128, 256, 0, stream>>>(h, W1tp, cvec, hwp, N);
  k_spmm2<<<(N + 3) / 4, 256, 0, stream>>>((const unsigned int*)hwp, adj, col, rp, b1,
                                           outd, N);
}